// Round 12
// baseline (311.868 us; speedup 1.0000x reference)
//
#include <hip/hip_runtime.h>
#include <math.h>

#define N_ 512
#define B_ 128
#define EPSV 1e-20f
#define ITERS 80
#define CONV_TOL 1e-4f

typedef __attribute__((ext_vector_type(8))) unsigned short ushort8;
typedef _Float16 __attribute__((ext_vector_type(2))) half2_t;
typedef __fp16 __attribute__((ext_vector_type(2))) fp16v2;

#if defined(__has_builtin)
#if __has_builtin(__builtin_amdgcn_fdot2)
#define HAS_FDOT2 1
#endif
#endif

static __device__ __forceinline__ float dot2f(unsigned int a, unsigned int b, float acc) {
    union { unsigned int u; half2_t h; } ua, ub;
    ua.u = a; ub.u = b;
#ifdef HAS_FDOT2
    return __builtin_amdgcn_fdot2(ua.h, ub.h, acc, false);
#else
    return acc + (float)ua.h[0] * (float)ub.h[0] + (float)ua.h[1] * (float)ub.h[1];
#endif
}
static __device__ __forceinline__ unsigned int pk16(float lo, float hi) {
    union { fp16v2 h; unsigned int u; } c;
    c.h = __builtin_amdgcn_cvt_pkrtz(lo, hi);
    return c.u;
}
static __device__ __forceinline__ unsigned short f2h(float x) {   // RNE f32->f16
    union { _Float16 h; unsigned short s; } c; c.h = (_Float16)x; return c.s;
}
static __device__ __forceinline__ float h2f(unsigned int u, int hi) {
    union { unsigned int u; half2_t h; } c; c.u = u;
    return hi ? (float)c.h[1] : (float)c.h[0];
}
static __device__ __forceinline__ float bf2f(unsigned short h) {
    union { unsigned int u; float f; } c; c.u = ((unsigned int)h) << 16; return c.f;
}
static __device__ __forceinline__ unsigned short f2bf(float f) {
    union { float f; unsigned int u; } c; c.f = f;
    unsigned int r = (c.u + 0x7FFFu + ((c.u >> 16) & 1u)) >> 16;
    return (unsigned short)r;
}
static __device__ __forceinline__ float frcp(float x) {
    return __builtin_amdgcn_rcpf(x);
}

// ---- wave-per-row P0 computation (pure shuffles, no LDS) ----
static __device__ __forceinline__ void compute_row(
    const float* __restrict__ logits, const float* __restrict__ u1,
    size_t base, int lane, float inv_tau, float p[8])
{
    const float4* Lp = (const float4*)(logits + base);
    const float4* Up = (const float4*)(u1 + base);
    const float4 l0 = Lp[2*lane], l1 = Lp[2*lane+1];
    const float4 q0 = Up[2*lane], q1 = Up[2*lane+1];
    float L[8] = {l0.x,l0.y,l0.z,l0.w,l1.x,l1.y,l1.z,l1.w};
    float U[8] = {q0.x,q0.y,q0.z,q0.w,q1.x,q1.y,q1.z,q1.w};

    float x[8];
    #pragma unroll
    for (int k = 0; k < 8; ++k) {
        float g = -__logf(-__logf(U[k] + 1e-20f) + 1e-20f);
        x[k] = (L[k] + g) * inv_tau;
    }
    float m = x[0];
    #pragma unroll
    for (int k = 1; k < 8; ++k) m = fmaxf(m, x[k]);
    #pragma unroll
    for (int off = 32; off; off >>= 1) m = fmaxf(m, __shfl_xor(m, off));
    float e[8], s = 0.0f;
    #pragma unroll
    for (int k = 0; k < 8; ++k) { e[k] = __expf(x[k] - m); s += e[k]; }
    #pragma unroll
    for (int off = 32; off; off >>= 1) s += __shfl_xor(s, off);
    const float rZ1 = frcp(s);
    float y[8];
    #pragma unroll
    for (int k = 0; k < 8; ++k) y[k] = L[k] + 0.015f * (e[k] * rZ1);
    float m2 = y[0];
    #pragma unroll
    for (int k = 1; k < 8; ++k) m2 = fmaxf(m2, y[k]);
    #pragma unroll
    for (int off = 32; off; off >>= 1) m2 = fmaxf(m2, __shfl_xor(m2, off));
    float f[8], z = 0.0f;
    #pragma unroll
    for (int k = 0; k < 8; ++k) { f[k] = __expf(y[k] - m2); z += f[k]; }
    #pragma unroll
    for (int off = 32; off; off >>= 1) z += __shfl_xor(z, off);
    const float rZ2 = frcp(z);
    #pragma unroll
    for (int k = 0; k < 8; ++k) p[k] = f[k] * rZ2;
}

// ---------------- Kernel 1 (main): P0 -> two f16 copies ----------------
// 1024 thr = 16 waves = 16 rows per block (wave-per-row). Via a 16KB LDS
// stage, writes: R (row-pair interleaved: uint = {M[2rp][c], M[2rp+1][c]})
// and T (transposed col-pair interleaved: uint = {M[r][2cp], M[r][2cp+1]}).
__global__ __launch_bounds__(1024) void setup_f16(
    const float* __restrict__ logits,
    const float* __restrict__ u1,
    const int* __restrict__ steps_p,
    unsigned int* __restrict__ R,
    unsigned int* __restrict__ T)
{
    const int wave = threadIdx.x >> 6;
    const int lane = threadIdx.x & 63;
    const int blk  = blockIdx.x;
    const int row  = (blk << 4) + wave;                 // global row
    const size_t base = (size_t)row << 9;

    const float stepsf = (float)(*steps_p);
    const float inv_tau = frcp(fmaxf(__expf(stepsf * -1.0000500033e-4f), 0.1f));

    float p[8];
    compute_row(logits, u1, base, lane, inv_tau, p);

    __shared__ unsigned short st[16][N_];               // 16 KB f16 stage
    {
        ushort8 o;
        #pragma unroll
        for (int k = 0; k < 8; ++k) o[k] = f2h(p[k]);
        *(ushort8*)&st[wave][lane << 3] = o;
    }
    __syncthreads();

    const int mat   = blk >> 5;                         // 32 blocks per matrix
    const int lrow0 = (blk & 31) << 4;                  // first local row
    const size_t mb4 = ((size_t)mat) << 15;             // uint4 base per matrix

    // R: thread t -> local row-pair rpl=t>>7, col-quad idx=t&127
    {
        const int rpl = threadIdx.x >> 7;               // 0..7
        const int idx = threadIdx.x & 127;
        const int a = rpl << 1, bq = a + 1;
        const int c = idx << 2;
        uint4 w;
        w.x = (unsigned int)st[a][c]   | ((unsigned int)st[bq][c])   << 16;
        w.y = (unsigned int)st[a][c+1] | ((unsigned int)st[bq][c+1]) << 16;
        w.z = (unsigned int)st[a][c+2] | ((unsigned int)st[bq][c+2]) << 16;
        w.w = (unsigned int)st[a][c+3] | ((unsigned int)st[bq][c+3]) << 16;
        const int rp = ((lrow0 >> 1) + rpl);            // row-pair local to matrix
        ((uint4*)R)[mb4 + (size_t)rp * 128 + idx] = w;
    }
    // T: thread t -> col-pair cp=t>>2, row-quad q=t&3
    {
        const int cp = threadIdx.x >> 2;                // 0..255
        const int q  = threadIdx.x & 3;
        const int r0 = q << 2;
        const int c  = cp << 1;
        uint4 w;
        w.x = (unsigned int)st[r0][c]   | ((unsigned int)st[r0][c+1])   << 16;
        w.y = (unsigned int)st[r0+1][c] | ((unsigned int)st[r0+1][c+1]) << 16;
        w.z = (unsigned int)st[r0+2][c] | ((unsigned int)st[r0+2][c+1]) << 16;
        w.w = (unsigned int)st[r0+3][c] | ((unsigned int)st[r0+3][c+1]) << 16;
        ((uint4*)T)[mb4 + (size_t)cp * 128 + ((lrow0 >> 2) + q)] = w;
    }
}

// ---------------- Kernel 2 (main): bpermute-free f16 Sinkhorn ----------------
// 128 blocks x 1024 thr. Pass1 over T: lane owns 8 PRIVATE rows -> row sums
// are lane-local dot2 accumulations, NO cross-lane reduce. Pass2 over R:
// lane owns 8 private cols. 16-wave LDS tree combine for both. Inner loop has
// ZERO ds_bpermute (rounds 3/9/10 were LDS-pipe-bound on 192 of them/lane/iter
// -> constant 122us regardless of bytes or load count).
__global__ __launch_bounds__(1024) void sinkhorn_f16(
    const unsigned int* __restrict__ R,
    const unsigned int* __restrict__ T,
    float* __restrict__ Out)
{
    const int b = blockIdx.x;
    const uint4* __restrict__ R4 = (const uint4*)R + (((size_t)b) << 15);
    const uint4* __restrict__ T4 = (const uint4*)T + (((size_t)b) << 15);
    float* __restrict__ O = Out + (((size_t)b) << 18);

    const int tid  = threadIdx.x;
    const int lane = tid & 63;
    const int wave = tid >> 6;            // 0..15
    const int e0 = lane << 2;             // lane's first private row/col

    __shared__ float u_s[N_];
    __shared__ float v_s[N_];
    __shared__ unsigned int u2_s[N_/2];   // packed f16 pairs {u[2i],u[2i+1]}
    __shared__ unsigned int v2_s[N_/2];
    __shared__ float cpart[16][N_];       // 32 KB combine buffer
    __shared__ float wmax[8];

    if (tid < N_) { u_s[tid] = 1.0f; v_s[tid] = 1.0f; }
    if (tid < N_/2) v2_s[tid] = 0x3C003C00u;            // pack(1,1)
    __syncthreads();

    for (int it = 0; it < ITERS; ++it) {
        // ---------- pass 1: u (row sums via T) ----------
        {
            const uint4 a0 = ((const uint4*)&v2_s[wave << 4])[0];
            const uint4 a1 = ((const uint4*)&v2_s[wave << 4])[1];
            const uint4 a2 = ((const uint4*)&v2_s[wave << 4])[2];
            const uint4 a3 = ((const uint4*)&v2_s[wave << 4])[3];
            unsigned int v2r[16];
            v2r[0]=a0.x; v2r[1]=a0.y; v2r[2]=a0.z; v2r[3]=a0.w;
            v2r[4]=a1.x; v2r[5]=a1.y; v2r[6]=a1.z; v2r[7]=a1.w;
            v2r[8]=a2.x; v2r[9]=a2.y; v2r[10]=a2.z; v2r[11]=a2.w;
            v2r[12]=a3.x; v2r[13]=a3.y; v2r[14]=a3.z; v2r[15]=a3.w;

            float s0=0.f,s1=0.f,s2=0.f,s3=0.f,s4=0.f,s5=0.f,s6=0.f,s7=0.f;
            #pragma unroll
            for (int pp = 0; pp < 16; ++pp) {
                const size_t cb = (size_t)((wave << 4) + pp) * 128;
                const uint4 Wa = T4[cb + lane];
                const uint4 Wb = T4[cb + 64 + lane];
                const unsigned int vv = v2r[pp];
                s0 = dot2f(Wa.x, vv, s0); s1 = dot2f(Wa.y, vv, s1);
                s2 = dot2f(Wa.z, vv, s2); s3 = dot2f(Wa.w, vv, s3);
                s4 = dot2f(Wb.x, vv, s4); s5 = dot2f(Wb.y, vv, s5);
                s6 = dot2f(Wb.z, vv, s6); s7 = dot2f(Wb.w, vv, s7);
            }
            *(float4*)&cpart[wave][e0]       = make_float4(s0, s1, s2, s3);
            *(float4*)&cpart[wave][e0 + 256] = make_float4(s4, s5, s6, s7);
        }
        __syncthreads();                                 // A

        if (tid < N_) {
            float S = 0.0f;
            #pragma unroll
            for (int w = 0; w < 16; ++w) S += cpart[w][tid];
            const float uo = u_s[tid];
            const float un = (uo * S > EPSV) ? frcp(S) : uo;   // faithful row>EPS guard
            u_s[tid] = un;
            const float pn = __shfl_xor(un, 1);
            if (!(tid & 1)) u2_s[tid >> 1] = pk16(un, pn);
        }
        __syncthreads();                                 // B

        // ---------- pass 2: v (col sums via R, new u) ----------
        {
            const uint4 a0 = ((const uint4*)&u2_s[wave << 4])[0];
            const uint4 a1 = ((const uint4*)&u2_s[wave << 4])[1];
            const uint4 a2 = ((const uint4*)&u2_s[wave << 4])[2];
            const uint4 a3 = ((const uint4*)&u2_s[wave << 4])[3];
            unsigned int u2r[16];
            u2r[0]=a0.x; u2r[1]=a0.y; u2r[2]=a0.z; u2r[3]=a0.w;
            u2r[4]=a1.x; u2r[5]=a1.y; u2r[6]=a1.z; u2r[7]=a1.w;
            u2r[8]=a2.x; u2r[9]=a2.y; u2r[10]=a2.z; u2r[11]=a2.w;
            u2r[12]=a3.x; u2r[13]=a3.y; u2r[14]=a3.z; u2r[15]=a3.w;

            float c0=0.f,c1=0.f,c2=0.f,c3=0.f,c4=0.f,c5=0.f,c6=0.f,c7=0.f;
            #pragma unroll
            for (int pp = 0; pp < 16; ++pp) {
                const size_t rb = (size_t)((wave << 4) + pp) * 128;
                const uint4 Wa = R4[rb + lane];
                const uint4 Wb = R4[rb + 64 + lane];
                const unsigned int uu = u2r[pp];
                c0 = dot2f(Wa.x, uu, c0); c1 = dot2f(Wa.y, uu, c1);
                c2 = dot2f(Wa.z, uu, c2); c3 = dot2f(Wa.w, uu, c3);
                c4 = dot2f(Wb.x, uu, c4); c5 = dot2f(Wb.y, uu, c5);
                c6 = dot2f(Wb.z, uu, c6); c7 = dot2f(Wb.w, uu, c7);
            }
            *(float4*)&cpart[wave][e0]       = make_float4(c0, c1, c2, c3);
            *(float4*)&cpart[wave][e0 + 256] = make_float4(c4, c5, c6, c7);
        }
        __syncthreads();                                 // C

        float mrel = 0.0f;
        if (tid < N_) {
            float C = 0.0f;
            #pragma unroll
            for (int w = 0; w < 16; ++w) C += cpart[w][tid];
            const float vo = v_s[tid];
            const float vn = (vo * C > EPSV) ? frcp(C) : vo;   // faithful col>EPS guard
            v_s[tid] = vn;
            const float pn = __shfl_xor(vn, 1);
            if (!(tid & 1)) v2_s[tid >> 1] = pk16(vn, pn);
            mrel = fabsf(vn - vo) * frcp(vo);
        }
        #pragma unroll
        for (int off = 32; off; off >>= 1) mrel = fmaxf(mrel, __shfl_xor(mrel, off));
        if (lane == 0 && wave < 8) wmax[wave] = mrel;
        __syncthreads();                                 // D

        float mx = wmax[0];
        #pragma unroll
        for (int w = 1; w < 8; ++w) mx = fmaxf(mx, wmax[w]);
        if (mx < CONV_TOL) break;                        // uniform; deterministic
    }

    // ---------- final: Out = clip(P0 * u_i * v_j, EPS, 1) from R ----------
    const float4 va = *(const float4*)&v_s[e0];
    const float4 vb = *(const float4*)&v_s[e0 + 256];
    const float vA[4] = {va.x, va.y, va.z, va.w};
    const float vB[4] = {vb.x, vb.y, vb.z, vb.w};

    #pragma unroll 4
    for (int pp = 0; pp < 16; ++pp) {
        const int rp = (wave << 4) + pp;
        const size_t rb = (size_t)rp * 128;
        const uint4 Wa = R4[rb + lane];
        const uint4 Wb = R4[rb + 64 + lane];
        const float u0 = u_s[2 * rp], u1v = u_s[2 * rp + 1];
        const unsigned int wa[4] = {Wa.x, Wa.y, Wa.z, Wa.w};
        const unsigned int wb[4] = {Wb.x, Wb.y, Wb.z, Wb.w};
        float eA[4], oA[4], eB[4], oB[4];
        #pragma unroll
        for (int j = 0; j < 4; ++j) {
            eA[j] = fminf(fmaxf(h2f(wa[j], 0) * u0  * vA[j], EPSV), 1.0f);
            oA[j] = fminf(fmaxf(h2f(wa[j], 1) * u1v * vA[j], EPSV), 1.0f);
            eB[j] = fminf(fmaxf(h2f(wb[j], 0) * u0  * vB[j], EPSV), 1.0f);
            oB[j] = fminf(fmaxf(h2f(wb[j], 1) * u1v * vB[j], EPSV), 1.0f);
        }
        const size_t r0 = (size_t)(2 * rp) << 9;
        *(float4*)&O[r0 + e0]             = make_float4(eA[0], eA[1], eA[2], eA[3]);
        *(float4*)&O[r0 + 512 + e0]       = make_float4(oA[0], oA[1], oA[2], oA[3]);
        *(float4*)&O[r0 + e0 + 256]       = make_float4(eB[0], eB[1], eB[2], eB[3]);
        *(float4*)&O[r0 + 512 + e0 + 256] = make_float4(oB[0], oB[1], oB[2], oB[3]);
    }
}

// ===================== Fallback setup (bf16 / f32) ===========================
template <int MODE>   // 0: f32->out, 1: bf16->P0h
__global__ __launch_bounds__(256) void setup_legacy(
    const float* __restrict__ logits,
    const float* __restrict__ u1,
    const int* __restrict__ steps_p,
    float* __restrict__ P0f,
    unsigned short* __restrict__ P0h)
{
    const int wave = threadIdx.x >> 6;
    const int lane = threadIdx.x & 63;
    const int row  = (blockIdx.x << 2) + wave;
    const size_t base = (size_t)row << 9;

    const float stepsf = (float)(*steps_p);
    const float inv_tau = frcp(fmaxf(__expf(stepsf * -1.0000500033e-4f), 0.1f));

    float p[8];
    compute_row(logits, u1, base, lane, inv_tau, p);

    const int c0 = lane << 3;
    if (MODE == 0) {
        float4* dst = (float4*)(P0f + base + c0);
        dst[0] = make_float4(p[0], p[1], p[2], p[3]);
        dst[1] = make_float4(p[4], p[5], p[6], p[7]);
    } else {
        ushort8 o;
        #pragma unroll
        for (int k = 0; k < 8; ++k) o[k] = f2bf(p[k]);
        *(ushort8*)(P0h + base + c0) = o;
    }
}

// ---------------- Proven round-3 bf16 fallback ----------------
__global__ __launch_bounds__(1024) void sinkhorn_bf16(
    const unsigned short* __restrict__ Pb, float* __restrict__ Out)
{
    const int b = blockIdx.x;
    const unsigned short* __restrict__ M = Pb + ((size_t)b << 18);
    float* __restrict__ O = Out + ((size_t)b << 18);

    const int tid = threadIdx.x;
    const int lane = tid & 63;
    const int wave = tid >> 6;
    const int c0 = lane << 3;
    const int rbase = wave << 5;

    __shared__ float u_s[N_];
    __shared__ float v_s[N_];
    __shared__ float cpart[16][N_];
    __shared__ float wmax[8];

    if (tid < N_) { u_s[tid] = 1.0f; v_s[tid] = 1.0f; }
    __syncthreads();

    for (int it = 0; it < ITERS; ++it) {
        float vr[8];
        #pragma unroll
        for (int k = 0; k < 8; ++k) vr[k] = v_s[c0 + k];
        float ca[8] = {0.f,0.f,0.f,0.f,0.f,0.f,0.f,0.f};

        #pragma unroll 4
        for (int rr = 0; rr < 32; ++rr) {
            const int r = rbase + rr;
            ushort8 h = *(const ushort8*)(M + ((size_t)r << 9) + c0);
            float x[8];
            #pragma unroll
            for (int k = 0; k < 8; ++k) x[k] = bf2f(h[k]);
            float d = x[0]*vr[0] + x[1]*vr[1] + x[2]*vr[2] + x[3]*vr[3]
                    + x[4]*vr[4] + x[5]*vr[5] + x[6]*vr[6] + x[7]*vr[7];
            #pragma unroll
            for (int off = 32; off; off >>= 1) d += __shfl_xor(d, off);
            const float uo = u_s[r];
            const float un = (uo * d > EPSV) ? frcp(d) : uo;
            if (lane == 0) u_s[r] = un;
            #pragma unroll
            for (int k = 0; k < 8; ++k) ca[k] += x[k] * un;
        }
        #pragma unroll
        for (int k = 0; k < 8; ++k) cpart[wave][c0 + k] = ca[k];
        __syncthreads();

        float mrel = 0.0f;
        if (tid < N_) {
            float c = 0.0f;
            #pragma unroll
            for (int w = 0; w < 16; ++w) c += cpart[w][tid];
            const float vo = v_s[tid];
            const float vn = (vo * c > EPSV) ? frcp(c) : vo;
            v_s[tid] = vn;
            mrel = fabsf(vn - vo) * frcp(vo);
        }
        #pragma unroll
        for (int off = 32; off; off >>= 1) mrel = fmaxf(mrel, __shfl_xor(mrel, off));
        if (lane == 0 && wave < 8) wmax[wave] = mrel;
        __syncthreads();

        float mx = wmax[0];
        #pragma unroll
        for (int w = 1; w < 8; ++w) mx = fmaxf(mx, wmax[w]);
        if (mx < CONV_TOL) break;
    }

    float vrf[8];
    #pragma unroll
    for (int k = 0; k < 8; ++k) vrf[k] = v_s[c0 + k];
    for (int rr = 0; rr < 32; ++rr) {
        const int r = rbase + rr;
        ushort8 h = *(const ushort8*)(M + ((size_t)r << 9) + c0);
        const float ur = u_s[r];
        float o[8];
        #pragma unroll
        for (int k = 0; k < 8; ++k)
            o[k] = fminf(fmaxf(bf2f(h[k]) * ur * vrf[k], EPSV), 1.0f);
        float4* dst = (float4*)(O + ((size_t)r << 9) + c0);
        dst[0] = make_float4(o[0], o[1], o[2], o[3]);
        dst[1] = make_float4(o[4], o[5], o[6], o[7]);
    }
}

// ---------------- Tiny-ws fallback: fp32 in-place ------------------------------
__global__ __launch_bounds__(1024) void sinkhorn_f32(float* __restrict__ P)
{
    const int b = blockIdx.x;
    float* __restrict__ M = P + (size_t)b * N_ * N_;
    float4* __restrict__ M4 = (float4*)M;

    const int tid = threadIdx.x;
    const int lane = tid & 63;
    const int wave = tid >> 6;
    const int jb = tid & 127;
    const int rq = tid >> 7;

    __shared__ float4 u4s[N_ / 4];
    __shared__ float4 v4s[N_ / 4];
    __shared__ float4 cpartf[1024];
    float* u = (float*)u4s;
    float* v = (float*)v4s;

    if (tid < N_) { u[tid] = 1.0f; v[tid] = 1.0f; }
    __syncthreads();

    for (int it = 0; it < 150; ++it) {
        for (int r = wave; r < N_; r += 16) {
            const float4* row4 = M4 + (size_t)r * (N_ / 4);
            float4 a = row4[lane];
            float4 bq = row4[lane + 64];
            float4 va = v4s[lane];
            float4 vb = v4s[lane + 64];
            float acc = a.x*va.x + a.y*va.y + a.z*va.z + a.w*va.w
                      + bq.x*vb.x + bq.y*vb.y + bq.z*vb.z + bq.w*vb.w;
            #pragma unroll
            for (int off = 32; off; off >>= 1) acc += __shfl_xor(acc, off);
            if (lane == 0) {
                float uo = u[r];
                u[r] = (uo * acc > EPSV) ? (1.0f / acc) : uo;
            }
        }
        __syncthreads();

        float4 acc4 = make_float4(0.f, 0.f, 0.f, 0.f);
        for (int r = rq; r < N_; r += 8) {
            float4 mrow = M4[(size_t)r * (N_ / 4) + jb];
            float ur = u[r];
            acc4.x += mrow.x * ur; acc4.y += mrow.y * ur;
            acc4.z += mrow.z * ur; acc4.w += mrow.w * ur;
        }
        cpartf[tid] = acc4;
        __syncthreads();
        if (tid < 128) {
            float4 cs = cpartf[tid];
            #pragma unroll
            for (int k = 1; k < 8; ++k) {
                float4 p = cpartf[tid + (k << 7)];
                cs.x += p.x; cs.y += p.y; cs.z += p.z; cs.w += p.w;
            }
            float vo0 = v[4*tid+0], vo1 = v[4*tid+1], vo2 = v[4*tid+2], vo3 = v[4*tid+3];
            v[4*tid+0] = (vo0 * cs.x > EPSV) ? (1.0f / cs.x) : vo0;
            v[4*tid+1] = (vo1 * cs.y > EPSV) ? (1.0f / cs.y) : vo1;
            v[4*tid+2] = (vo2 * cs.z > EPSV) ? (1.0f / cs.z) : vo2;
            v[4*tid+3] = (vo3 * cs.w > EPSV) ? (1.0f / cs.w) : vo3;
        }
        __syncthreads();
    }

    for (int r = rq; r < N_; r += 8) {
        size_t idx = (size_t)r * (N_ / 4) + jb;
        float4 mrow = M4[idx];
        float ur = u[r];
        float4 vv = v4s[jb];
        mrow.x = fminf(fmaxf(mrow.x * ur * vv.x, EPSV), 1.0f);
        mrow.y = fminf(fmaxf(mrow.y * ur * vv.y, EPSV), 1.0f);
        mrow.z = fminf(fmaxf(mrow.z * ur * vv.z, EPSV), 1.0f);
        mrow.w = fminf(fmaxf(mrow.w * ur * vv.w, EPSV), 1.0f);
        M4[idx] = mrow;
    }
}

extern "C" void kernel_launch(void* const* d_in, const int* in_sizes, int n_in,
                              void* d_out, int out_size, void* d_ws, size_t ws_size,
                              hipStream_t stream) {
    const float* logits = (const float*)d_in[0];
    const float* u1     = (const float*)d_in[1];
    // d_in[2] (u2) is dead in the forward value: st - stop_gradient(st) == 0.
    const int* steps    = (const int*)d_in[3];
    float* out = (float*)d_out;

    const size_t nelem    = (size_t)B_ * N_ * N_;          // 32Mi elements
    const size_t nu       = nelem >> 1;                     // uints per f16 copy
    const size_t need_f16 = 2 * nelem * 2;                  // 128 MB: R + T
    const size_t need_bf16 = nelem * 2;                     // 64 MB

    if (ws_size >= need_f16) {
        unsigned int* R = (unsigned int*)d_ws;
        unsigned int* T = R + nu;
        setup_f16<<<B_ * N_ / 16, 1024, 0, stream>>>(logits, u1, steps, R, T);
        sinkhorn_f16<<<B_, 1024, 0, stream>>>(R, T, out);
    } else if (ws_size >= need_bf16) {
        unsigned short* P0h = (unsigned short*)d_ws;
        setup_legacy<1><<<B_ * N_ / 4, 256, 0, stream>>>(logits, u1, steps, nullptr, P0h);
        sinkhorn_bf16<<<B_, 1024, 0, stream>>>(P0h, out);
    } else {
        setup_legacy<0><<<B_ * N_ / 4, 256, 0, stream>>>(logits, u1, steps, out, nullptr);
        sinkhorn_f32<<<B_, 1024, 0, stream>>>(out);
    }
}